// Round 1
// baseline (154.923 us; speedup 1.0000x reference)
//
#include <hip/hip_runtime.h>
#include <math.h>

// Net_90434831385322: z = A + span*sigmoid(relu((x-A)/span @ W1 + b1) @ W2 + b2)
// BATCH=4194304, OBS=4, HID=64, ACT=4, all fp32.
//
// Strategy: fold input scaling into W1/b1 once per launch (prep kernel into
// d_ws), then a fused per-row MLP kernel: 8 rows/thread, weights broadcast
// from LDS (uniform-address ds_read = free broadcast), fp32 FMA chain.

#define BATCH   4194304
#define HID     64
#define ROWS    8
#define TPB     256
#define NBLK    (BATCH / (TPB * ROWS))   // 2048

// ws layout (floats):
//   [0   .. 255]  W1' as float4 per j: {W1'[0][j], W1'[1][j], W1'[2][j], W1'[3][j]}
//   [256 .. 511]  W2  as float4 per j: {W2[j][0..3]}  (already row-major)
//   [512 .. 575]  b1'[j]
//   [576 .. 579]  b2[0..3]
#define WS_FLOATS 580

__global__ __launch_bounds__(64)
void prep_kernel(const float* __restrict__ W1, const float* __restrict__ b1,
                 const float* __restrict__ W2, const float* __restrict__ b2,
                 float* __restrict__ ws) {
    const float A[4] = {0.001f, 0.02f, 0.05f, 0.001f};
    const float S[4] = {0.003f, 0.03f, 0.15f, 0.003f};  // span = B - A
    int j = threadIdx.x;           // 0..63
    if (j < HID) {
        float bb = b1[j];
        #pragma unroll
        for (int k = 0; k < 4; ++k) {
            float wv = W1[k * HID + j];
            ws[j * 4 + k] = wv / S[k];          // W1' = W1 / span (row-scaled)
            bb -= (A[k] / S[k]) * wv;           // b1' = b1 - (A/span)@W1
        }
        ws[512 + j] = bb;
        #pragma unroll
        for (int i = 0; i < 4; ++i)
            ws[256 + j * 4 + i] = W2[j * 4 + i];
    }
    if (j < 4) ws[576 + j] = b2[j];
}

__global__ __launch_bounds__(TPB)
void mlp_kernel(const float* __restrict__ x, const float* __restrict__ ws,
                float* __restrict__ out) {
    __shared__ float s[WS_FLOATS];
    for (int i = threadIdx.x; i < WS_FLOATS; i += TPB) s[i] = ws[i];
    __syncthreads();

    const float4* sW1 = (const float4*)(s);
    const float4* sW2 = (const float4*)(s + 256);
    const float*  sB1 = s + 512;
    const float*  sB2 = s + 576;

    const long base = (long)blockIdx.x * (TPB * ROWS) + threadIdx.x;
    const float4* __restrict__ x4   = (const float4*)x;
    float4* __restrict__       out4 = (float4*)out;

    // Load 8 rows up front (coalesced dwordx4, hides HBM latency behind compute)
    float4 xr[ROWS];
    #pragma unroll
    for (int r = 0; r < ROWS; ++r) xr[r] = x4[base + (long)r * TPB];

    const float b2x = sB2[0], b2y = sB2[1], b2z = sB2[2], b2w = sB2[3];
    float4 acc[ROWS];
    #pragma unroll
    for (int r = 0; r < ROWS; ++r) acc[r] = make_float4(b2x, b2y, b2z, b2w);

    // Fused hidden loop: h_j = relu(w1.x + b); acc += h_j * w2_j
    #pragma unroll 4
    for (int j = 0; j < HID; ++j) {
        const float4 w1 = sW1[j];
        const float4 w2 = sW2[j];
        const float  b  = sB1[j];
        #pragma unroll
        for (int r = 0; r < ROWS; ++r) {
            float t = fmaf(xr[r].x, w1.x, b);
            t = fmaf(xr[r].y, w1.y, t);
            t = fmaf(xr[r].z, w1.z, t);
            t = fmaf(xr[r].w, w1.w, t);
            t = fmaxf(t, 0.0f);
            acc[r].x = fmaf(t, w2.x, acc[r].x);
            acc[r].y = fmaf(t, w2.y, acc[r].y);
            acc[r].z = fmaf(t, w2.z, acc[r].z);
            acc[r].w = fmaf(t, w2.w, acc[r].w);
        }
    }

    // z = A + span * sigmoid(y) = A + span / (1 + exp(-y))
    const float A0 = 0.001f, A1 = 0.02f, A2 = 0.05f, A3 = 0.001f;
    const float S0 = 0.003f, S1 = 0.03f, S2 = 0.15f, S3 = 0.003f;
    #pragma unroll
    for (int r = 0; r < ROWS; ++r) {
        float4 z;
        z.x = A0 + S0 / (1.0f + __expf(-acc[r].x));
        z.y = A1 + S1 / (1.0f + __expf(-acc[r].y));
        z.z = A2 + S2 / (1.0f + __expf(-acc[r].z));
        z.w = A3 + S3 / (1.0f + __expf(-acc[r].w));
        out4[base + (long)r * TPB] = z;
    }
}

extern "C" void kernel_launch(void* const* d_in, const int* in_sizes, int n_in,
                              void* d_out, int out_size, void* d_ws, size_t ws_size,
                              hipStream_t stream) {
    const float* x  = (const float*)d_in[0];
    const float* W1 = (const float*)d_in[1];
    const float* b1 = (const float*)d_in[2];
    const float* W2 = (const float*)d_in[3];
    const float* b2 = (const float*)d_in[4];
    float* out = (float*)d_out;
    float* ws  = (float*)d_ws;

    prep_kernel<<<1, 64, 0, stream>>>(W1, b1, W2, b2, ws);
    mlp_kernel<<<NBLK, TPB, 0, stream>>>(x, ws, out);
}